// Round 18
// baseline (231.260 us; speedup 1.0000x reference)
//
#include <hip/hip_runtime.h>
#include <hip/hip_bf16.h>

#define DEVI __device__ __forceinline__

typedef __attribute__((ext_vector_type(8))) short bf16x8;
typedef __attribute__((ext_vector_type(4))) float f32x4;
typedef __attribute__((ext_vector_type(2))) unsigned u32x2;

static constexpr int BB = 16, CC = 512, NT = 784, HD = 8, DH = 32;
static constexpr int INNER = 256, HID = 2048, MTOT = BB * NT; // 12544

DEVI short f2bf(float x) {
  unsigned u = __builtin_bit_cast(unsigned, x);
  u += 0x7fffu + ((u >> 16) & 1u);
  return (short)(u >> 16);
}

DEVI unsigned pack2bf(float lo, float hi) {
  return ((unsigned)(unsigned short)f2bf(lo)) | ((unsigned)(unsigned short)f2bf(hi) << 16);
}

DEVI void gll16(const void* g, void* l) {
  __builtin_amdgcn_global_load_lds(
      (const __attribute__((address_space(1))) unsigned int*)g,
      (__attribute__((address_space(3))) unsigned int*)l, 16, 0, 0);
}

// ---------------- mega-prep: weight transposes + x-transpose + bias table ---
__device__ void wprep_body(const float* __restrict__ W, short* __restrict__ WT,
                           int K0, int N0, int bx, int by, float* smem) {
  float (*tile)[33] = (float(*)[33])smem;
  const int tk0 = bx * 32, tn0 = by * 32;
  const int tx = threadIdx.x & 31, ty = threadIdx.x >> 5;  // 32 x 8
#pragma unroll
  for (int i = 0; i < 4; ++i)
    tile[ty + i * 8][tx] = W[(size_t)(tk0 + ty + i * 8) * N0 + tn0 + tx];
  __syncthreads();
#pragma unroll
  for (int i = 0; i < 4; ++i)
    WT[(size_t)(tn0 + ty + i * 8) * K0 + tk0 + tx] = f2bf(tile[tx][ty + i * 8]);
}

__global__ void prep_kernel(const float* __restrict__ qkv_w, short* __restrict__ wqkvT,
                            const float* __restrict__ out_w, short* __restrict__ woutT,
                            const float* __restrict__ ff_w1, short* __restrict__ wf1T,
                            const float* __restrict__ ff_w2, short* __restrict__ wf2T,
                            const float* __restrict__ x, float* __restrict__ xs,
                            const float* __restrict__ rel, short* __restrict__ bt) {
  __shared__ float smem[64 * 17];
  const int bid = blockIdx.x;
  if (bid < 384) {
    wprep_body(qkv_w, wqkvT, 512, 768, bid & 15, bid >> 4, smem);
  } else if (bid < 512) {
    int l = bid - 384;
    wprep_body(out_w, woutT, 256, 512, l & 7, l >> 3, smem);
  } else if (bid < 1536) {
    int l = bid - 512;
    wprep_body(ff_w1, wf1T, 512, 2048, l & 15, l >> 4, smem);
  } else if (bid < 2560) {
    int l = bid - 1536;
    wprep_body(ff_w2, wf2T, 2048, 512, l & 63, l >> 6, smem);
  } else if (bid < 8832) {
    int l = bid - 2560;
    float (*tile)[17] = (float(*)[17])smem;
    const int n0 = (l % 49) * 16, c0 = ((l / 49) & 7) * 64, b = l / 392;
    const int tx = threadIdx.x & 15, ty = threadIdx.x >> 4;  // 16 x 16
    const float* p = x + ((size_t)b * CC + c0) * NT + n0;
#pragma unroll
    for (int i = 0; i < 4; ++i)
      tile[ty + i * 16][tx] = p[(size_t)(ty + i * 16) * NT + tx];
    __syncthreads();
    float* qd = xs + ((size_t)b * NT + n0) * CC + c0;
    const int cx = threadIdx.x & 63, ny = threadIdx.x >> 6;  // 64 x 4
#pragma unroll
    for (int i = 0; i < 4; ++i)
      qd[(size_t)(ny + i * 4) * CC + cx] = tile[cx][ny + i * 4];
  } else {
    // biastab (swapped-QK layout): bt[h][qc13][jblk49][wid][lane][r]
    //   i = qc*64 + wid*16 + (lane&15)            (clamped to 783)
    //   j = jblk*16 + (lane>>4)*4 + r
    int id = (bid - 8832) * 256 + threadIdx.x;  // 8*13*49*4*64*4 = 5218304
    int r = id & 3;
    int lane = (id >> 2) & 63;
    int wid = (id >> 8) & 3;
    int t = id >> 10;          // jblk + 49*(qc + 13*h)
    int jblk = t % 49;
    int t2 = t / 49;
    int qc = t2 % 13;
    int h = t2 / 13;
    int i = qc * 64 + wid * 16 + (lane & 15);
    if (i > 783) i = 783;
    int j = jblk * 16 + ((lane >> 4) << 2) + r;
    int hi_ = i / 28, wi_ = i - hi_ * 28;
    int hj = j / 28, wj = j - hj * 28;
    int ridx = (hi_ - hj + 27) * 55 + (wi_ - wj + 27);
    bt[id] = f2bf(rel[ridx * 8 + h] * 1.4426950408889634f);
  }
}

// ---------------- LayerNorm (block = 1 token, 256 thr, C=512, coalesced) ----
__global__ void ln_kernel(const float* __restrict__ in, const float* __restrict__ gw,
                          const float* __restrict__ bw, short* __restrict__ h_out) {
  int t = blockIdx.x;
  int tid = threadIdx.x;
  const float* p = in + (size_t)t * CC;
  float v0 = p[tid], v1 = p[tid + 256];
  float s = v0 + v1, s2 = v0 * v0 + v1 * v1;
#pragma unroll
  for (int m = 1; m < 64; m <<= 1) {
    s += __shfl_xor(s, m);
    s2 += __shfl_xor(s2, m);
  }
  __shared__ float red[8];
  int wid = tid >> 6;
  if ((tid & 63) == 0) { red[wid] = s; red[4 + wid] = s2; }
  __syncthreads();
  s = red[0] + red[1] + red[2] + red[3];
  s2 = red[4] + red[5] + red[6] + red[7];
  float mu = s * (1.f / 512.f);
  float var = s2 * (1.f / 512.f) - mu * mu;
  float rs = rsqrtf(var + 1e-5f);
  h_out[(size_t)t * CC + tid] = f2bf((v0 - mu) * rs * gw[tid] + bw[tid]);
  h_out[(size_t)t * CC + tid + 256] = f2bf((v1 - mu) * rs * gw[tid + 256] + bw[tid + 256]);
}

// ---------------- GEMM: C[m][n] = sum_k A[m][k] * BT[n][k] ------------------
// Single-buffer, T2 XOR-swizzled LDS (generalized to CHUNKS=BK/8 chunk bits),
// bijective XCD-chunk swizzle (n-fastest). BK=64 or 128.
template <int EPI, int BM, int BN, int BK, int MINW>
__global__ __launch_bounds__(256, MINW) void gemm_bt(
    const short* __restrict__ A, const short* __restrict__ BT,
    const float* __restrict__ bias, int K, void* __restrict__ out0,
    void* __restrict__ o1, void* __restrict__ o2, const float* __restrict__ res,
    int Nld, int nn) {
  __shared__ short As[BM * BK];
  __shared__ short Bs[BN * BK];
  const int tid = threadIdx.x;
  const int lane = tid & 63, wid = tid >> 6;
  const int nwg = gridDim.x, orig = blockIdx.x;
  const int q = nwg >> 3, rm = nwg & 7;
  const int xcd = orig & 7, idx = orig >> 3;
  const int wg = (xcd < rm) ? (xcd * (q + 1) + idx)
                            : (rm * (q + 1) + (xcd - rm) * q + idx);
  const int mt = wg / nn, nt = wg - mt * nn;
  const int m0 = mt * BM, n0 = nt * BN;
  const int wm = wid >> 1, wn = wid & 1;
  constexpr int MF = BM >> 5;
  constexpr int NF = BN >> 5;
  constexpr int CHUNKS = BK / 8;                 // 16B chunks per row
  constexpr int CMASK = CHUNKS - 1;
  constexpr int ACALLS = (BM * CHUNKS) / 256;
  constexpr int BCALLS = (BN * CHUNKS) / 256;
  const int lg = lane >> 4, ln = lane & 15;

  f32x4 acc[MF][NF] = {};
  for (int kt = 0; kt < K; kt += BK) {
#pragma unroll
    for (int call = 0; call < ACALLS; ++call) {
      int cb = call * 256 + (wid << 6);
      int c = cb + lane;
      int row = c / CHUNKS, j8 = c & CMASK;
      gll16(A + (size_t)(m0 + row) * K + kt + (j8 ^ (row & CMASK)) * 8, &As[cb * 8]);
    }
#pragma unroll
    for (int call = 0; call < BCALLS; ++call) {
      int cb = call * 256 + (wid << 6);
      int c = cb + lane;
      int row = c / CHUNKS, j8 = c & CMASK;
      gll16(BT + (size_t)(n0 + row) * K + kt + (j8 ^ (row & CMASK)) * 8, &Bs[cb * 8]);
    }
    __syncthreads();
#pragma unroll
    for (int kk = 0; kk < BK; kk += 32) {
      bf16x8 af[MF], bfr[NF];
#pragma unroll
      for (int mf = 0; mf < MF; ++mf) {
        int r = wm * (BM >> 1) + mf * 16 + ln;
        af[mf] = *(const bf16x8*)&As[r * BK + ((((kk >> 3) + lg) ^ (r & CMASK)) << 3)];
      }
#pragma unroll
      for (int nf = 0; nf < NF; ++nf) {
        int r = wn * (BN >> 1) + nf * 16 + ln;
        bfr[nf] = *(const bf16x8*)&Bs[r * BK + ((((kk >> 3) + lg) ^ (r & CMASK)) << 3)];
      }
#pragma unroll
      for (int mf = 0; mf < MF; ++mf)
#pragma unroll
        for (int nf = 0; nf < NF; ++nf)
          acc[mf][nf] = __builtin_amdgcn_mfma_f32_16x16x32_bf16(af[mf], bfr[nf], acc[mf][nf], 0, 0, 0);
    }
    __syncthreads();
  }
#pragma unroll
  for (int mf = 0; mf < MF; ++mf)
#pragma unroll
    for (int nf = 0; nf < NF; ++nf) {
      int col = n0 + wn * (BN >> 1) + nf * 16 + ln;
      float bv = bias[col];
#pragma unroll
      for (int r = 0; r < 4; ++r) {
        int row = m0 + wm * (BM >> 1) + mf * 16 + lg * 4 + r;
        float val = acc[mf][nf][r] + bv;
        if (EPI == 0) {
          int which = col >> 8, head = (col >> 5) & 7, dd = col & 31;
          int b = row / NT, n = row - b * NT;
          if (which == 2) {
            ((short*)o2)[((size_t)((b * HD + head) * DH + dd)) * NT + n] = f2bf(val);
          } else {
            short* dst = (which == 0) ? (short*)out0 : (short*)o1;
            dst[((size_t)((b * HD + head) * NT + n)) * DH + dd] = f2bf(val);
          }
        } else if (EPI == 1) {
          ((float*)out0)[(size_t)row * Nld + col] = val + res[(size_t)row * Nld + col];
        } else if (EPI == 2) {
          float v2 = val * val;
          float y = val * fmaf(0.102944458f, v2, 2.30225813f);
          y = fminf(y, 80.f);
          float e = __builtin_amdgcn_exp2f(y);
          float gl = val * e * __builtin_amdgcn_rcpf(e + 1.0f);
          ((short*)out0)[(size_t)row * Nld + col] = f2bf(gl);
        } else {
          int b = row / NT, n = row - b * NT;
          ((float*)out0)[((size_t)(b * CC + col)) * NT + n] =
              val + res[(size_t)row * Nld + col];
        }
      }
    }
}

// ---------------- attention: fixed-max flash, QBLK=64, swapped-QK ----------
__global__ __launch_bounds__(256, 3) void attn_kernel(
    const short* __restrict__ qb, const short* __restrict__ kb,
    const short* __restrict__ vtg, const short* __restrict__ bt,
    short* __restrict__ ob) {
  const int qc = blockIdx.x;  // 0..12
  const int bh = blockIdx.y;  // 0..127
  const int b = bh >> 3, h = bh & 7;
  const int tid = threadIdx.x, lane = tid & 63, wid = tid >> 6;
  const int lg = lane >> 4, ln = lane & 15;
  const int rb = qc * 64 + wid * 16;  // wave's q-row base
  const float SC2 = 0.17677669529663687f * 1.4426950408889634f;  // scale*log2e

  __shared__ short Pl[4][16 * 136];  // per-wave P tile (16 q-rows)
  short* pw = Pl[wid];

  const short* qrow = qb + (size_t)bh * NT * DH;
  bf16x8 aq;
  {
    int r = rb + ln;
    if (r > 783) r = 783;
    aq = *(const bf16x8*)(qrow + (size_t)r * DH + lg * 8);
  }
  float l_acc = 0.f;
  f32x4 o_acc[2] = {};
  const short* kbase = kb + (size_t)bh * NT * DH;
  const short* vbase = vtg + (size_t)bh * DH * NT;
  const short* btw = bt + ((size_t)(h * 13 + qc) * 49) * 1024 + wid * 256 + lane * 4;

  bf16x8 kcur[8];
#pragma unroll
  for (int nf = 0; nf < 8; ++nf)
    kcur[nf] = *(const bf16x8*)(kbase + (size_t)(nf * 16 + ln) * DH + lg * 8);

  for (int jt = 0; jt < 768; jt += 128) {
    const int jt0 = jt >> 4;
    bf16x8 knext[8];
#pragma unroll
    for (int nf = 0; nf < 8; ++nf) {
      int j = jt + 128 + nf * 16 + ln;
      if (j > 783) j = 783;
      knext[nf] = *(const bf16x8*)(kbase + (size_t)j * DH + lg * 8);
    }
    bf16x8 vreg[4][2];
#pragma unroll
    for (int kk = 0; kk < 4; ++kk)
#pragma unroll
      for (int dr = 0; dr < 2; ++dr)
        vreg[kk][dr] = *(const bf16x8*)(vbase + (size_t)(dr * 16 + ln) * NT + jt + kk * 32 + lg * 8);

#pragma unroll
    for (int nf = 0; nf < 8; ++nf) {
      const u32x2 bq = *(const u32x2*)(btw + (size_t)(jt0 + nf) * 1024);
      f32x4 zr = {0.f, 0.f, 0.f, 0.f};
      f32x4 s = __builtin_amdgcn_mfma_f32_16x16x32_bf16(kcur[nf], aq, zr, 0, 0, 0);
      unsigned w0 = bq.x, w1 = bq.y;
      float p0 = __builtin_amdgcn_exp2f(fmaf(s[0], SC2, __builtin_bit_cast(float, w0 << 16)));
      float p1 = __builtin_amdgcn_exp2f(fmaf(s[1], SC2, __builtin_bit_cast(float, w0 & 0xffff0000u)));
      float p2 = __builtin_amdgcn_exp2f(fmaf(s[2], SC2, __builtin_bit_cast(float, w1 << 16)));
      float p3 = __builtin_amdgcn_exp2f(fmaf(s[3], SC2, __builtin_bit_cast(float, w1 & 0xffff0000u)));
      l_acc += (p0 + p1) + (p2 + p3);
      u32x2 pk = {pack2bf(p0, p1), pack2bf(p2, p3)};
      *(u32x2*)&pw[ln * 136 + nf * 16 + (lg << 2)] = pk;
    }
#pragma unroll
    for (int kk = 0; kk < 4; ++kk) {
      bf16x8 ap = *(const bf16x8*)&pw[ln * 136 + kk * 32 + lg * 8];
#pragma unroll
      for (int dr = 0; dr < 2; ++dr)
        o_acc[dr] = __builtin_amdgcn_mfma_f32_16x16x32_bf16(ap, vreg[kk][dr], o_acc[dr], 0, 0, 0);
    }
#pragma unroll
    for (int nf = 0; nf < 8; ++nf) kcur[nf] = knext[nf];
  }

  // ---- tail tile jt=768 (16 valid columns; kcur[0] holds exact rows 768..783)
  {
    {
      u32x2 zz = {0u, 0u};
      *(u32x2*)&pw[ln * 136 + 16 + (lg << 2)] = zz;  // zero cols 16..31
    }
    const u32x2 bq = *(const u32x2*)(btw + (size_t)48 * 1024);
    f32x4 zr = {0.f, 0.f, 0.f, 0.f};
    f32x4 s = __builtin_amdgcn_mfma_f32_16x16x32_bf16(kcur[0], aq, zr, 0, 0, 0);
    unsigned w0 = bq.x, w1 = bq.y;
    float p0 = __builtin_amdgcn_exp2f(fmaf(s[0], SC2, __builtin_bit_cast(float, w0 << 16)));
    float p1 = __builtin_amdgcn_exp2f(fmaf(s[1], SC2, __builtin_bit_cast(float, w0 & 0xffff0000u)));
    float p2 = __builtin_amdgcn_exp2f(fmaf(s[2], SC2, __builtin_bit_cast(float, w1 << 16)));
    float p3 = __builtin_amdgcn_exp2f(fmaf(s[3], SC2, __builtin_bit_cast(float, w1 & 0xffff0000u)));
    l_acc += (p0 + p1) + (p2 + p3);
    u32x2 pk = {pack2bf(p0, p1), pack2bf(p2, p3)};
    *(u32x2*)&pw[ln * 136 + (lg << 2)] = pk;
    {
      bf16x8 ap = *(const bf16x8*)&pw[ln * 136 + lg * 8];
      bf16x8 bv[2];
#pragma unroll
      for (int dr = 0; dr < 2; ++dr) {
        int col = 768 + lg * 8;
        if (col < NT)
          bv[dr] = *(const bf16x8*)(vbase + (size_t)(dr * 16 + ln) * NT + col);
        else {
          bf16x8 zz = {};
          bv[dr] = zz;
        }
      }
#pragma unroll
      for (int dr = 0; dr < 2; ++dr)
        o_acc[dr] = __builtin_amdgcn_mfma_f32_16x16x32_bf16(ap, bv[dr], o_acc[dr], 0, 0, 0);
    }
  }

  // ---- l reduce: sum over lg (lanes sharing ln), then gather per output row
  l_acc += __shfl_xor(l_acc, 16);
  l_acc += __shfl_xor(l_acc, 32);

  float rinv[4];
#pragma unroll
  for (int r = 0; r < 4; ++r) rinv[r] = 1.0f / __shfl(l_acc, lg * 4 + r);
#pragma unroll
  for (int dr = 0; dr < 2; ++dr)
#pragma unroll
    for (int r = 0; r < 4; ++r) {
      int row = rb + lg * 4 + r;
      if (row < 784) {
        float val = o_acc[dr][r] * rinv[r];
        ob[((size_t)(b * NT + row)) * INNER + h * DH + dr * 16 + ln] = f2bf(val);
      }
    }
}

// ---------------------------------------------------------------------------
extern "C" void kernel_launch(void* const* d_in, const int* in_sizes, int n_in,
                              void* d_out, int out_size, void* d_ws, size_t ws_size,
                              hipStream_t stream) {
  const float* x = (const float*)d_in[0];
  const float* ln1_g = (const float*)d_in[1];
  const float* ln1_b = (const float*)d_in[2];
  const float* qkv_w = (const float*)d_in[3];
  const float* qkv_b = (const float*)d_in[4];
  const float* out_w = (const float*)d_in[5];
  const float* out_b = (const float*)d_in[6];
  const float* rel_table = (const float*)d_in[7];
  const float* ln2_g = (const float*)d_in[8];
  const float* ln2_b = (const float*)d_in[9];
  const float* ff_w1 = (const float*)d_in[10];
  const float* ff_b1 = (const float*)d_in[11];
  const float* ff_w2 = (const float*)d_in[12];
  const float* ff_b2 = (const float*)d_in[13];
  float* out = (float*)d_out;
  char* ws = (char*)d_ws;

  constexpr size_t OFF_XS = 0;          // f32 [12544][512]
  constexpr size_t OFF_H = 25690112;    // bf16 [12544][512]
  constexpr size_t OFF_WQKV = 38535168; // bf16 [768][512]
  constexpr size_t OFF_WOUT = 39321600; // bf16 [512][256]
  constexpr size_t OFF_WF1 = 39583744;  // bf16 [2048][512]
  constexpr size_t OFF_WF2 = 41680896;  // bf16 [512][2048]
  constexpr size_t OFF_Q = 43778048;    // bf16 [128][784][32]
  constexpr size_t OFF_K = 50200576;
  constexpr size_t OFF_VT = 63045632;   // bf16 [128][32][784]
  constexpr size_t OFF_O = 69468160;    // bf16 [12544][256]
  constexpr size_t OFF_XS2 = 75890688;  // f32 [12544][512]; bias table lives here pre-attn
  constexpr size_t OFF_G = 101580800;   // bf16 [12544][2048]

  float* xs = (float*)(ws + OFF_XS);
  short* h = (short*)(ws + OFF_H);
  short* wqkvT = (short*)(ws + OFF_WQKV);
  short* woutT = (short*)(ws + OFF_WOUT);
  short* wf1T = (short*)(ws + OFF_WF1);
  short* wf2T = (short*)(ws + OFF_WF2);
  short* qb = (short*)(ws + OFF_Q);
  short* kb = (short*)(ws + OFF_K);
  short* vt = (short*)(ws + OFF_VT);
  short* ob = (short*)(ws + OFF_O);
  short* bt = (short*)(ws + OFF_XS2);   // bf16 QBLK=64 table, 10.4 MB (dead after attn)
  float* xs2 = (float*)(ws + OFF_XS2);
  short* g = (short*)(ws + OFF_G);

  // mega-prep: all weight transposes + x-transpose + bias table in one launch
  prep_kernel<<<29216, 256, 0, stream>>>(qkv_w, wqkvT, out_w, woutT,
                                         ff_w1, wf1T, ff_w2, wf2T,
                                         x, xs, rel_table, bt);

  // LN1 coalesced (reads xs written by prep)
  ln_kernel<<<MTOT, 256, 0, stream>>>(xs, ln1_g, ln1_b, h);

  // QKV (V written directly transposed; BN=64 -> grid 1176)
  gemm_bt<0, 128, 64, 64, 3><<<1176, 256, 0, stream>>>(h, wqkvT, qkv_b, 512, qb, kb, vt, nullptr, 0, 12);

  // attention (QBLK=64, swapped-QK; grid 13x128)
  attn_kernel<<<dim3(13, 128), 256, 0, stream>>>(qb, kb, vt, bt, ob);

  // out-proj + residual -> xs2   (N=512, BN=64 -> grid 784)
  gemm_bt<1, 128, 64, 64, 3><<<784, 256, 0, stream>>>(ob, woutT, out_b, 256, xs2, nullptr, nullptr, xs, 512, 8);

  // LN2 -> h2
  ln_kernel<<<MTOT, 256, 0, stream>>>(xs2, ln2_g, ln2_b, h);

  // FFN1 + fast GELU -> g
  gemm_bt<2, 128, 128, 64, 3><<<1568, 256, 0, stream>>>(h, wf1T, ff_b1, 512, g, nullptr, nullptr, nullptr, 2048, 16);

  // FFN2 + residual -> out (transposed write; BK=128 -> 16 K-steps, 4-bit swizzle)
  gemm_bt<3, 128, 64, 128, 3><<<784, 256, 0, stream>>>(g, wf2T, ff_b2, 2048, out, nullptr, nullptr, xs2, 512, 8);
}

// Round 19
// 223.673 us; speedup vs baseline: 1.0339x; 1.0339x over previous
//
#include <hip/hip_runtime.h>
#include <hip/hip_bf16.h>

#define DEVI __device__ __forceinline__

typedef __attribute__((ext_vector_type(8))) short bf16x8;
typedef __attribute__((ext_vector_type(4))) float f32x4;
typedef __attribute__((ext_vector_type(2))) unsigned u32x2;

static constexpr int BB = 16, CC = 512, NT = 784, HD = 8, DH = 32;
static constexpr int INNER = 256, HID = 2048, MTOT = BB * NT; // 12544

DEVI short f2bf(float x) {
  unsigned u = __builtin_bit_cast(unsigned, x);
  u += 0x7fffu + ((u >> 16) & 1u);
  return (short)(u >> 16);
}

DEVI unsigned pack2bf(float lo, float hi) {
  return ((unsigned)(unsigned short)f2bf(lo)) | ((unsigned)(unsigned short)f2bf(hi) << 16);
}

DEVI void gll16(const void* g, void* l) {
  __builtin_amdgcn_global_load_lds(
      (const __attribute__((address_space(1))) unsigned int*)g,
      (__attribute__((address_space(3))) unsigned int*)l, 16, 0, 0);
}

// ---------------- mega-prep: weight transposes + x-transpose + bias table ---
__device__ void wprep_body(const float* __restrict__ W, short* __restrict__ WT,
                           int K0, int N0, int bx, int by, float* smem) {
  float (*tile)[33] = (float(*)[33])smem;
  const int tk0 = bx * 32, tn0 = by * 32;
  const int tx = threadIdx.x & 31, ty = threadIdx.x >> 5;  // 32 x 8
#pragma unroll
  for (int i = 0; i < 4; ++i)
    tile[ty + i * 8][tx] = W[(size_t)(tk0 + ty + i * 8) * N0 + tn0 + tx];
  __syncthreads();
#pragma unroll
  for (int i = 0; i < 4; ++i)
    WT[(size_t)(tn0 + ty + i * 8) * K0 + tk0 + tx] = f2bf(tile[tx][ty + i * 8]);
}

__global__ void prep_kernel(const float* __restrict__ qkv_w, short* __restrict__ wqkvT,
                            const float* __restrict__ out_w, short* __restrict__ woutT,
                            const float* __restrict__ ff_w1, short* __restrict__ wf1T,
                            const float* __restrict__ ff_w2, short* __restrict__ wf2T,
                            const float* __restrict__ x, float* __restrict__ xs,
                            const float* __restrict__ rel, short* __restrict__ bt) {
  __shared__ float smem[64 * 17];
  const int bid = blockIdx.x;
  if (bid < 384) {
    wprep_body(qkv_w, wqkvT, 512, 768, bid & 15, bid >> 4, smem);
  } else if (bid < 512) {
    int l = bid - 384;
    wprep_body(out_w, woutT, 256, 512, l & 7, l >> 3, smem);
  } else if (bid < 1536) {
    int l = bid - 512;
    wprep_body(ff_w1, wf1T, 512, 2048, l & 15, l >> 4, smem);
  } else if (bid < 2560) {
    int l = bid - 1536;
    wprep_body(ff_w2, wf2T, 2048, 512, l & 63, l >> 6, smem);
  } else if (bid < 8832) {
    int l = bid - 2560;
    float (*tile)[17] = (float(*)[17])smem;
    const int n0 = (l % 49) * 16, c0 = ((l / 49) & 7) * 64, b = l / 392;
    const int tx = threadIdx.x & 15, ty = threadIdx.x >> 4;  // 16 x 16
    const float* p = x + ((size_t)b * CC + c0) * NT + n0;
#pragma unroll
    for (int i = 0; i < 4; ++i)
      tile[ty + i * 16][tx] = p[(size_t)(ty + i * 16) * NT + tx];
    __syncthreads();
    float* qd = xs + ((size_t)b * NT + n0) * CC + c0;
    const int cx = threadIdx.x & 63, ny = threadIdx.x >> 6;  // 64 x 4
#pragma unroll
    for (int i = 0; i < 4; ++i)
      qd[(size_t)(ny + i * 4) * CC + cx] = tile[cx][ny + i * 4];
  } else {
    // biastab (swapped-QK layout): bt[h][qc13][jblk49][wid][lane][r]
    //   i = qc*64 + wid*16 + (lane&15)            (clamped to 783)
    //   j = jblk*16 + (lane>>4)*4 + r
    int id = (bid - 8832) * 256 + threadIdx.x;  // 8*13*49*4*64*4 = 5218304
    int r = id & 3;
    int lane = (id >> 2) & 63;
    int wid = (id >> 8) & 3;
    int t = id >> 10;          // jblk + 49*(qc + 13*h)
    int jblk = t % 49;
    int t2 = t / 49;
    int qc = t2 % 13;
    int h = t2 / 13;
    int i = qc * 64 + wid * 16 + (lane & 15);
    if (i > 783) i = 783;
    int j = jblk * 16 + ((lane >> 4) << 2) + r;
    int hi_ = i / 28, wi_ = i - hi_ * 28;
    int hj = j / 28, wj = j - hj * 28;
    int ridx = (hi_ - hj + 27) * 55 + (wi_ - wj + 27);
    bt[id] = f2bf(rel[ridx * 8 + h] * 1.4426950408889634f);
  }
}

// ---------------- LayerNorm (block = 1 token, 256 thr, C=512, coalesced) ----
__global__ void ln_kernel(const float* __restrict__ in, const float* __restrict__ gw,
                          const float* __restrict__ bw, short* __restrict__ h_out) {
  int t = blockIdx.x;
  int tid = threadIdx.x;
  const float* p = in + (size_t)t * CC;
  float v0 = p[tid], v1 = p[tid + 256];
  float s = v0 + v1, s2 = v0 * v0 + v1 * v1;
#pragma unroll
  for (int m = 1; m < 64; m <<= 1) {
    s += __shfl_xor(s, m);
    s2 += __shfl_xor(s2, m);
  }
  __shared__ float red[8];
  int wid = tid >> 6;
  if ((tid & 63) == 0) { red[wid] = s; red[4 + wid] = s2; }
  __syncthreads();
  s = red[0] + red[1] + red[2] + red[3];
  s2 = red[4] + red[5] + red[6] + red[7];
  float mu = s * (1.f / 512.f);
  float var = s2 * (1.f / 512.f) - mu * mu;
  float rs = rsqrtf(var + 1e-5f);
  h_out[(size_t)t * CC + tid] = f2bf((v0 - mu) * rs * gw[tid] + bw[tid]);
  h_out[(size_t)t * CC + tid + 256] = f2bf((v1 - mu) * rs * gw[tid + 256] + bw[tid + 256]);
}

// ---------------- GEMM: C[m][n] = sum_k A[m][k] * BT[n][k] ------------------
// Single-buffer, T2 XOR-swizzled LDS (CHUNKS=BK/8 chunk bits),
// bijective XCD-chunk swizzle (n-fastest). BK=64.
template <int EPI, int BM, int BN, int BK, int MINW>
__global__ __launch_bounds__(256, MINW) void gemm_bt(
    const short* __restrict__ A, const short* __restrict__ BT,
    const float* __restrict__ bias, int K, void* __restrict__ out0,
    void* __restrict__ o1, void* __restrict__ o2, const float* __restrict__ res,
    int Nld, int nn) {
  __shared__ short As[BM * BK];
  __shared__ short Bs[BN * BK];
  const int tid = threadIdx.x;
  const int lane = tid & 63, wid = tid >> 6;
  const int nwg = gridDim.x, orig = blockIdx.x;
  const int q = nwg >> 3, rm = nwg & 7;
  const int xcd = orig & 7, idx = orig >> 3;
  const int wg = (xcd < rm) ? (xcd * (q + 1) + idx)
                            : (rm * (q + 1) + (xcd - rm) * q + idx);
  const int mt = wg / nn, nt = wg - mt * nn;
  const int m0 = mt * BM, n0 = nt * BN;
  const int wm = wid >> 1, wn = wid & 1;
  constexpr int MF = BM >> 5;
  constexpr int NF = BN >> 5;
  constexpr int CHUNKS = BK / 8;                 // 16B chunks per row
  constexpr int CMASK = CHUNKS - 1;
  constexpr int ACALLS = (BM * CHUNKS) / 256;
  constexpr int BCALLS = (BN * CHUNKS) / 256;
  const int lg = lane >> 4, ln = lane & 15;

  f32x4 acc[MF][NF] = {};
  for (int kt = 0; kt < K; kt += BK) {
#pragma unroll
    for (int call = 0; call < ACALLS; ++call) {
      int cb = call * 256 + (wid << 6);
      int c = cb + lane;
      int row = c / CHUNKS, j8 = c & CMASK;
      gll16(A + (size_t)(m0 + row) * K + kt + (j8 ^ (row & CMASK)) * 8, &As[cb * 8]);
    }
#pragma unroll
    for (int call = 0; call < BCALLS; ++call) {
      int cb = call * 256 + (wid << 6);
      int c = cb + lane;
      int row = c / CHUNKS, j8 = c & CMASK;
      gll16(BT + (size_t)(n0 + row) * K + kt + (j8 ^ (row & CMASK)) * 8, &Bs[cb * 8]);
    }
    __syncthreads();
#pragma unroll
    for (int kk = 0; kk < BK; kk += 32) {
      bf16x8 af[MF], bfr[NF];
#pragma unroll
      for (int mf = 0; mf < MF; ++mf) {
        int r = wm * (BM >> 1) + mf * 16 + ln;
        af[mf] = *(const bf16x8*)&As[r * BK + ((((kk >> 3) + lg) ^ (r & CMASK)) << 3)];
      }
#pragma unroll
      for (int nf = 0; nf < NF; ++nf) {
        int r = wn * (BN >> 1) + nf * 16 + ln;
        bfr[nf] = *(const bf16x8*)&Bs[r * BK + ((((kk >> 3) + lg) ^ (r & CMASK)) << 3)];
      }
#pragma unroll
      for (int mf = 0; mf < MF; ++mf)
#pragma unroll
        for (int nf = 0; nf < NF; ++nf)
          acc[mf][nf] = __builtin_amdgcn_mfma_f32_16x16x32_bf16(af[mf], bfr[nf], acc[mf][nf], 0, 0, 0);
    }
    __syncthreads();
  }
#pragma unroll
  for (int mf = 0; mf < MF; ++mf)
#pragma unroll
    for (int nf = 0; nf < NF; ++nf) {
      int col = n0 + wn * (BN >> 1) + nf * 16 + ln;
      float bv = bias[col];
#pragma unroll
      for (int r = 0; r < 4; ++r) {
        int row = m0 + wm * (BM >> 1) + mf * 16 + lg * 4 + r;
        float val = acc[mf][nf][r] + bv;
        if (EPI == 0) {
          int which = col >> 8, head = (col >> 5) & 7, dd = col & 31;
          int b = row / NT, n = row - b * NT;
          if (which == 2) {
            ((short*)o2)[((size_t)((b * HD + head) * DH + dd)) * NT + n] = f2bf(val);
          } else {
            short* dst = (which == 0) ? (short*)out0 : (short*)o1;
            dst[((size_t)((b * HD + head) * NT + n)) * DH + dd] = f2bf(val);
          }
        } else if (EPI == 1) {
          ((float*)out0)[(size_t)row * Nld + col] = val + res[(size_t)row * Nld + col];
        } else if (EPI == 2) {
          float v2 = val * val;
          float y = val * fmaf(0.102944458f, v2, 2.30225813f);
          y = fminf(y, 80.f);
          float e = __builtin_amdgcn_exp2f(y);
          float gl = val * e * __builtin_amdgcn_rcpf(e + 1.0f);
          ((short*)out0)[(size_t)row * Nld + col] = f2bf(gl);
        } else {
          int b = row / NT, n = row - b * NT;
          ((float*)out0)[((size_t)(b * CC + col)) * NT + n] =
              val + res[(size_t)row * Nld + col];
        }
      }
    }
}

// ---------------- attention: fixed-max flash, QBLK=64, swapped-QK ----------
__global__ __launch_bounds__(256, 3) void attn_kernel(
    const short* __restrict__ qb, const short* __restrict__ kb,
    const short* __restrict__ vtg, const short* __restrict__ bt,
    short* __restrict__ ob) {
  const int qc = blockIdx.x;  // 0..12
  const int bh = blockIdx.y;  // 0..127
  const int b = bh >> 3, h = bh & 7;
  const int tid = threadIdx.x, lane = tid & 63, wid = tid >> 6;
  const int lg = lane >> 4, ln = lane & 15;
  const int rb = qc * 64 + wid * 16;  // wave's q-row base
  const float SC2 = 0.17677669529663687f * 1.4426950408889634f;  // scale*log2e

  __shared__ short Pl[4][16 * 136];  // per-wave P tile (16 q-rows)
  short* pw = Pl[wid];

  const short* qrow = qb + (size_t)bh * NT * DH;
  bf16x8 aq;
  {
    int r = rb + ln;
    if (r > 783) r = 783;
    aq = *(const bf16x8*)(qrow + (size_t)r * DH + lg * 8);
  }
  float l_acc = 0.f;
  f32x4 o_acc[2] = {};
  const short* kbase = kb + (size_t)bh * NT * DH;
  const short* vbase = vtg + (size_t)bh * DH * NT;
  const short* btw = bt + ((size_t)(h * 13 + qc) * 49) * 1024 + wid * 256 + lane * 4;

  bf16x8 kcur[8];
#pragma unroll
  for (int nf = 0; nf < 8; ++nf)
    kcur[nf] = *(const bf16x8*)(kbase + (size_t)(nf * 16 + ln) * DH + lg * 8);

  for (int jt = 0; jt < 768; jt += 128) {
    const int jt0 = jt >> 4;
    bf16x8 knext[8];
#pragma unroll
    for (int nf = 0; nf < 8; ++nf) {
      int j = jt + 128 + nf * 16 + ln;
      if (j > 783) j = 783;
      knext[nf] = *(const bf16x8*)(kbase + (size_t)j * DH + lg * 8);
    }
    bf16x8 vreg[4][2];
#pragma unroll
    for (int kk = 0; kk < 4; ++kk)
#pragma unroll
      for (int dr = 0; dr < 2; ++dr)
        vreg[kk][dr] = *(const bf16x8*)(vbase + (size_t)(dr * 16 + ln) * NT + jt + kk * 32 + lg * 8);

#pragma unroll
    for (int nf = 0; nf < 8; ++nf) {
      const u32x2 bq = *(const u32x2*)(btw + (size_t)(jt0 + nf) * 1024);
      f32x4 zr = {0.f, 0.f, 0.f, 0.f};
      f32x4 s = __builtin_amdgcn_mfma_f32_16x16x32_bf16(kcur[nf], aq, zr, 0, 0, 0);
      unsigned w0 = bq.x, w1 = bq.y;
      float p0 = __builtin_amdgcn_exp2f(fmaf(s[0], SC2, __builtin_bit_cast(float, w0 << 16)));
      float p1 = __builtin_amdgcn_exp2f(fmaf(s[1], SC2, __builtin_bit_cast(float, w0 & 0xffff0000u)));
      float p2 = __builtin_amdgcn_exp2f(fmaf(s[2], SC2, __builtin_bit_cast(float, w1 << 16)));
      float p3 = __builtin_amdgcn_exp2f(fmaf(s[3], SC2, __builtin_bit_cast(float, w1 & 0xffff0000u)));
      l_acc += (p0 + p1) + (p2 + p3);
      u32x2 pk = {pack2bf(p0, p1), pack2bf(p2, p3)};
      *(u32x2*)&pw[ln * 136 + nf * 16 + (lg << 2)] = pk;
    }
#pragma unroll
    for (int kk = 0; kk < 4; ++kk) {
      bf16x8 ap = *(const bf16x8*)&pw[ln * 136 + kk * 32 + lg * 8];
#pragma unroll
      for (int dr = 0; dr < 2; ++dr)
        o_acc[dr] = __builtin_amdgcn_mfma_f32_16x16x32_bf16(ap, vreg[kk][dr], o_acc[dr], 0, 0, 0);
    }
#pragma unroll
    for (int nf = 0; nf < 8; ++nf) kcur[nf] = knext[nf];
  }

  // ---- tail tile jt=768 (16 valid columns; kcur[0] holds exact rows 768..783)
  {
    {
      u32x2 zz = {0u, 0u};
      *(u32x2*)&pw[ln * 136 + 16 + (lg << 2)] = zz;  // zero cols 16..31
    }
    const u32x2 bq = *(const u32x2*)(btw + (size_t)48 * 1024);
    f32x4 zr = {0.f, 0.f, 0.f, 0.f};
    f32x4 s = __builtin_amdgcn_mfma_f32_16x16x32_bf16(kcur[0], aq, zr, 0, 0, 0);
    unsigned w0 = bq.x, w1 = bq.y;
    float p0 = __builtin_amdgcn_exp2f(fmaf(s[0], SC2, __builtin_bit_cast(float, w0 << 16)));
    float p1 = __builtin_amdgcn_exp2f(fmaf(s[1], SC2, __builtin_bit_cast(float, w0 & 0xffff0000u)));
    float p2 = __builtin_amdgcn_exp2f(fmaf(s[2], SC2, __builtin_bit_cast(float, w1 << 16)));
    float p3 = __builtin_amdgcn_exp2f(fmaf(s[3], SC2, __builtin_bit_cast(float, w1 & 0xffff0000u)));
    l_acc += (p0 + p1) + (p2 + p3);
    u32x2 pk = {pack2bf(p0, p1), pack2bf(p2, p3)};
    *(u32x2*)&pw[ln * 136 + (lg << 2)] = pk;
    {
      bf16x8 ap = *(const bf16x8*)&pw[ln * 136 + lg * 8];
      bf16x8 bv[2];
#pragma unroll
      for (int dr = 0; dr < 2; ++dr) {
        int col = 768 + lg * 8;
        if (col < NT)
          bv[dr] = *(const bf16x8*)(vbase + (size_t)(dr * 16 + ln) * NT + col);
        else {
          bf16x8 zz = {};
          bv[dr] = zz;
        }
      }
#pragma unroll
      for (int dr = 0; dr < 2; ++dr)
        o_acc[dr] = __builtin_amdgcn_mfma_f32_16x16x32_bf16(ap, bv[dr], o_acc[dr], 0, 0, 0);
    }
  }

  // ---- l reduce: sum over lg (lanes sharing ln), then gather per output row
  l_acc += __shfl_xor(l_acc, 16);
  l_acc += __shfl_xor(l_acc, 32);

  float rinv[4];
#pragma unroll
  for (int r = 0; r < 4; ++r) rinv[r] = 1.0f / __shfl(l_acc, lg * 4 + r);
#pragma unroll
  for (int dr = 0; dr < 2; ++dr)
#pragma unroll
    for (int r = 0; r < 4; ++r) {
      int row = rb + lg * 4 + r;
      if (row < 784) {
        float val = o_acc[dr][r] * rinv[r];
        ob[((size_t)(b * NT + row)) * INNER + h * DH + dr * 16 + ln] = f2bf(val);
      }
    }
}

// ---------------------------------------------------------------------------
extern "C" void kernel_launch(void* const* d_in, const int* in_sizes, int n_in,
                              void* d_out, int out_size, void* d_ws, size_t ws_size,
                              hipStream_t stream) {
  const float* x = (const float*)d_in[0];
  const float* ln1_g = (const float*)d_in[1];
  const float* ln1_b = (const float*)d_in[2];
  const float* qkv_w = (const float*)d_in[3];
  const float* qkv_b = (const float*)d_in[4];
  const float* out_w = (const float*)d_in[5];
  const float* out_b = (const float*)d_in[6];
  const float* rel_table = (const float*)d_in[7];
  const float* ln2_g = (const float*)d_in[8];
  const float* ln2_b = (const float*)d_in[9];
  const float* ff_w1 = (const float*)d_in[10];
  const float* ff_b1 = (const float*)d_in[11];
  const float* ff_w2 = (const float*)d_in[12];
  const float* ff_b2 = (const float*)d_in[13];
  float* out = (float*)d_out;
  char* ws = (char*)d_ws;

  constexpr size_t OFF_XS = 0;          // f32 [12544][512]
  constexpr size_t OFF_H = 25690112;    // bf16 [12544][512]
  constexpr size_t OFF_WQKV = 38535168; // bf16 [768][512]
  constexpr size_t OFF_WOUT = 39321600; // bf16 [512][256]
  constexpr size_t OFF_WF1 = 39583744;  // bf16 [2048][512]
  constexpr size_t OFF_WF2 = 41680896;  // bf16 [512][2048]
  constexpr size_t OFF_Q = 43778048;    // bf16 [128][784][32]
  constexpr size_t OFF_K = 50200576;
  constexpr size_t OFF_VT = 63045632;   // bf16 [128][32][784]
  constexpr size_t OFF_O = 69468160;    // bf16 [12544][256]
  constexpr size_t OFF_XS2 = 75890688;  // f32 [12544][512]; bias table lives here pre-attn
  constexpr size_t OFF_G = 101580800;   // bf16 [12544][2048]

  float* xs = (float*)(ws + OFF_XS);
  short* h = (short*)(ws + OFF_H);
  short* wqkvT = (short*)(ws + OFF_WQKV);
  short* woutT = (short*)(ws + OFF_WOUT);
  short* wf1T = (short*)(ws + OFF_WF1);
  short* wf2T = (short*)(ws + OFF_WF2);
  short* qb = (short*)(ws + OFF_Q);
  short* kb = (short*)(ws + OFF_K);
  short* vt = (short*)(ws + OFF_VT);
  short* ob = (short*)(ws + OFF_O);
  short* bt = (short*)(ws + OFF_XS2);   // bf16 QBLK=64 table, 10.4 MB (dead after attn)
  float* xs2 = (float*)(ws + OFF_XS2);
  short* g = (short*)(ws + OFF_G);

  // mega-prep: all weight transposes + x-transpose + bias table in one launch
  prep_kernel<<<29216, 256, 0, stream>>>(qkv_w, wqkvT, out_w, woutT,
                                         ff_w1, wf1T, ff_w2, wf2T,
                                         x, xs, rel_table, bt);

  // LN1 coalesced (reads xs written by prep)
  ln_kernel<<<MTOT, 256, 0, stream>>>(xs, ln1_g, ln1_b, h);

  // QKV (V written directly transposed; BN=64 -> grid 1176)
  gemm_bt<0, 128, 64, 64, 3><<<1176, 256, 0, stream>>>(h, wqkvT, qkv_b, 512, qb, kb, vt, nullptr, 0, 12);

  // attention (QBLK=64, swapped-QK; grid 13x128)
  attn_kernel<<<dim3(13, 128), 256, 0, stream>>>(qb, kb, vt, bt, ob);

  // out-proj + residual -> xs2   (N=512, BN=64 -> grid 784)
  gemm_bt<1, 128, 64, 64, 3><<<784, 256, 0, stream>>>(ob, woutT, out_b, 256, xs2, nullptr, nullptr, xs, 512, 8);

  // LN2 -> h2
  ln_kernel<<<MTOT, 256, 0, stream>>>(xs2, ln2_g, ln2_b, h);

  // FFN1 + fast GELU -> g
  gemm_bt<2, 128, 128, 64, 3><<<1568, 256, 0, stream>>>(h, wf1T, ff_b1, 512, g, nullptr, nullptr, nullptr, 2048, 16);

  // FFN2 + residual -> out (transposed write; BK=64 -> best measured config)
  gemm_bt<3, 128, 64, 64, 3><<<784, 256, 0, stream>>>(g, wf2T, ff_b2, 2048, out, nullptr, nullptr, xs2, 512, 8);
}

// Round 20
// 219.889 us; speedup vs baseline: 1.0517x; 1.0172x over previous
//
#include <hip/hip_runtime.h>
#include <hip/hip_bf16.h>

#define DEVI __device__ __forceinline__

typedef __attribute__((ext_vector_type(8))) short bf16x8;
typedef __attribute__((ext_vector_type(4))) float f32x4;
typedef __attribute__((ext_vector_type(2))) unsigned u32x2;

static constexpr int BB = 16, CC = 512, NT = 784, HD = 8, DH = 32;
static constexpr int INNER = 256, HID = 2048, MTOT = BB * NT; // 12544

DEVI short f2bf(float x) {
  unsigned u = __builtin_bit_cast(unsigned, x);
  u += 0x7fffu + ((u >> 16) & 1u);
  return (short)(u >> 16);
}

DEVI unsigned pack2bf(float lo, float hi) {
  return ((unsigned)(unsigned short)f2bf(lo)) | ((unsigned)(unsigned short)f2bf(hi) << 16);
}

DEVI void gll16(const void* g, void* l) {
  __builtin_amdgcn_global_load_lds(
      (const __attribute__((address_space(1))) unsigned int*)g,
      (__attribute__((address_space(3))) unsigned int*)l, 16, 0, 0);
}

// ---------------- mega-prep: weight transposes + fused xtrans+LN1 + biastab -
// block ranges:
//   [0,384)       wprep qkv_w   [512][768]
//   [384,512)     wprep out_w   [256][512]
//   [512,1536)    wprep ff_w1   [512][2048]
//   [1536,2560)   wprep ff_w2   [2048][512]
//   [2560,3344)   fused x-transpose + LN1 (16 tokens/block)
//   [3344,23728)  biastab (swapped-QK layout)
__device__ void wprep_body(const float* __restrict__ W, short* __restrict__ WT,
                           int K0, int N0, int bx, int by, float* smem) {
  float (*tile)[33] = (float(*)[33])smem;
  const int tk0 = bx * 32, tn0 = by * 32;
  const int tx = threadIdx.x & 31, ty = threadIdx.x >> 5;  // 32 x 8
#pragma unroll
  for (int i = 0; i < 4; ++i)
    tile[ty + i * 8][tx] = W[(size_t)(tk0 + ty + i * 8) * N0 + tn0 + tx];
  __syncthreads();
#pragma unroll
  for (int i = 0; i < 4; ++i)
    WT[(size_t)(tn0 + ty + i * 8) * K0 + tk0 + tx] = f2bf(tile[tx][ty + i * 8]);
}

__global__ void prep_kernel(const float* __restrict__ qkv_w, short* __restrict__ wqkvT,
                            const float* __restrict__ out_w, short* __restrict__ woutT,
                            const float* __restrict__ ff_w1, short* __restrict__ wf1T,
                            const float* __restrict__ ff_w2, short* __restrict__ wf2T,
                            const float* __restrict__ x, float* __restrict__ xs,
                            const float* __restrict__ gw, const float* __restrict__ bw,
                            short* __restrict__ h1,
                            const float* __restrict__ rel, short* __restrict__ bt) {
  __shared__ float smem[512 * 17];
  __shared__ float stats[32];
  const int bid = blockIdx.x;
  if (bid < 384) {
    wprep_body(qkv_w, wqkvT, 512, 768, bid & 15, bid >> 4, smem);
  } else if (bid < 512) {
    int l = bid - 384;
    wprep_body(out_w, woutT, 256, 512, l & 7, l >> 3, smem);
  } else if (bid < 1536) {
    int l = bid - 512;
    wprep_body(ff_w1, wf1T, 512, 2048, l & 15, l >> 4, smem);
  } else if (bid < 2560) {
    int l = bid - 1536;
    wprep_body(ff_w2, wf2T, 2048, 512, l & 63, l >> 6, smem);
  } else if (bid < 3344) {
    // fused x-transpose + LN1: 16 tokens per block
    int l = bid - 2560;            // 0..783
    int b = l / 49, n0 = (l % 49) * 16;
    float (*tile)[17] = (float(*)[17])smem;  // [512 c][16 n, pad 17]
    const int tx = threadIdx.x & 15, ty = threadIdx.x >> 4;  // n, c-in-16
    const float* px = x + (size_t)b * CC * NT + n0;
#pragma unroll
    for (int c0 = 0; c0 < 512; c0 += 16)
      tile[c0 + ty][tx] = px[(size_t)(c0 + ty) * NT + tx];
    __syncthreads();
    // write xs (coalesced: lanes over c)
    float* qd = xs + ((size_t)b * NT + n0) * CC;
    const int c1 = threadIdx.x, c2 = threadIdx.x + 256;
#pragma unroll
    for (int nn = 0; nn < 16; ++nn) {
      qd[(size_t)nn * CC + c1] = tile[c1][nn];
      qd[(size_t)nn * CC + c2] = tile[c2][nn];
    }
    // LN stats: 16 threads per token (cl = c-lane, t = token)
    const int cl = threadIdx.x & 15, t = threadIdx.x >> 4;
    float s = 0.f, s2 = 0.f;
#pragma unroll
    for (int i = 0; i < 32; ++i) {
      float v = tile[cl + 16 * i][t];
      s += v;
      s2 += v * v;
    }
#pragma unroll
    for (int m = 1; m < 16; m <<= 1) {
      s += __shfl_xor(s, m);
      s2 += __shfl_xor(s2, m);
    }
    float mu = s * (1.f / 512.f);
    float var = s2 * (1.f / 512.f) - mu * mu;
    float rs = rsqrtf(var + 1e-5f);
    if (cl == 0) { stats[t] = mu; stats[16 + t] = rs; }
    __syncthreads();
    short* hd = h1 + ((size_t)b * NT + n0) * CC;
    const float g1 = gw[c1], b1 = bw[c1], g2 = gw[c2], b2 = bw[c2];
#pragma unroll
    for (int nn = 0; nn < 16; ++nn) {
      float m_ = stats[nn], r_ = stats[16 + nn];
      hd[(size_t)nn * CC + c1] = f2bf((tile[c1][nn] - m_) * r_ * g1 + b1);
      hd[(size_t)nn * CC + c2] = f2bf((tile[c2][nn] - m_) * r_ * g2 + b2);
    }
  } else {
    // biastab (swapped-QK layout): bt[h][qc13][jblk49][wid][lane][r]
    //   i = qc*64 + wid*16 + (lane&15)            (clamped to 783)
    //   j = jblk*16 + (lane>>4)*4 + r
    int id = (bid - 3344) * 256 + threadIdx.x;  // 8*13*49*4*64*4 = 5218304
    int r = id & 3;
    int lane = (id >> 2) & 63;
    int wid = (id >> 8) & 3;
    int t = id >> 10;          // jblk + 49*(qc + 13*h)
    int jblk = t % 49;
    int t2 = t / 49;
    int qc = t2 % 13;
    int h = t2 / 13;
    int i = qc * 64 + wid * 16 + (lane & 15);
    if (i > 783) i = 783;
    int j = jblk * 16 + ((lane >> 4) << 2) + r;
    int hi_ = i / 28, wi_ = i - hi_ * 28;
    int hj = j / 28, wj = j - hj * 28;
    int ridx = (hi_ - hj + 27) * 55 + (wi_ - wj + 27);
    bt[id] = f2bf(rel[ridx * 8 + h] * 1.4426950408889634f);
  }
}

// ---------------- LayerNorm (block = 1 token, 256 thr, C=512, coalesced) ----
__global__ void ln_kernel(const float* __restrict__ in, const float* __restrict__ gw,
                          const float* __restrict__ bw, short* __restrict__ h_out) {
  int t = blockIdx.x;
  int tid = threadIdx.x;
  const float* p = in + (size_t)t * CC;
  float v0 = p[tid], v1 = p[tid + 256];
  float s = v0 + v1, s2 = v0 * v0 + v1 * v1;
#pragma unroll
  for (int m = 1; m < 64; m <<= 1) {
    s += __shfl_xor(s, m);
    s2 += __shfl_xor(s2, m);
  }
  __shared__ float red[8];
  int wid = tid >> 6;
  if ((tid & 63) == 0) { red[wid] = s; red[4 + wid] = s2; }
  __syncthreads();
  s = red[0] + red[1] + red[2] + red[3];
  s2 = red[4] + red[5] + red[6] + red[7];
  float mu = s * (1.f / 512.f);
  float var = s2 * (1.f / 512.f) - mu * mu;
  float rs = rsqrtf(var + 1e-5f);
  h_out[(size_t)t * CC + tid] = f2bf((v0 - mu) * rs * gw[tid] + bw[tid]);
  h_out[(size_t)t * CC + tid + 256] = f2bf((v1 - mu) * rs * gw[tid + 256] + bw[tid + 256]);
}

// ---------------- GEMM: C[m][n] = sum_k A[m][k] * BT[n][k] ------------------
// Single-buffer, T2 XOR-swizzled LDS (CHUNKS=BK/8 chunk bits),
// bijective XCD-chunk swizzle (n-fastest). BK=64.
template <int EPI, int BM, int BN, int BK, int MINW>
__global__ __launch_bounds__(256, MINW) void gemm_bt(
    const short* __restrict__ A, const short* __restrict__ BT,
    const float* __restrict__ bias, int K, void* __restrict__ out0,
    void* __restrict__ o1, void* __restrict__ o2, const float* __restrict__ res,
    int Nld, int nn) {
  __shared__ short As[BM * BK];
  __shared__ short Bs[BN * BK];
  const int tid = threadIdx.x;
  const int lane = tid & 63, wid = tid >> 6;
  const int nwg = gridDim.x, orig = blockIdx.x;
  const int q = nwg >> 3, rm = nwg & 7;
  const int xcd = orig & 7, idx = orig >> 3;
  const int wg = (xcd < rm) ? (xcd * (q + 1) + idx)
                            : (rm * (q + 1) + (xcd - rm) * q + idx);
  const int mt = wg / nn, nt = wg - mt * nn;
  const int m0 = mt * BM, n0 = nt * BN;
  const int wm = wid >> 1, wn = wid & 1;
  constexpr int MF = BM >> 5;
  constexpr int NF = BN >> 5;
  constexpr int CHUNKS = BK / 8;                 // 16B chunks per row
  constexpr int CMASK = CHUNKS - 1;
  constexpr int ACALLS = (BM * CHUNKS) / 256;
  constexpr int BCALLS = (BN * CHUNKS) / 256;
  const int lg = lane >> 4, ln = lane & 15;

  f32x4 acc[MF][NF] = {};
  for (int kt = 0; kt < K; kt += BK) {
#pragma unroll
    for (int call = 0; call < ACALLS; ++call) {
      int cb = call * 256 + (wid << 6);
      int c = cb + lane;
      int row = c / CHUNKS, j8 = c & CMASK;
      gll16(A + (size_t)(m0 + row) * K + kt + (j8 ^ (row & CMASK)) * 8, &As[cb * 8]);
    }
#pragma unroll
    for (int call = 0; call < BCALLS; ++call) {
      int cb = call * 256 + (wid << 6);
      int c = cb + lane;
      int row = c / CHUNKS, j8 = c & CMASK;
      gll16(BT + (size_t)(n0 + row) * K + kt + (j8 ^ (row & CMASK)) * 8, &Bs[cb * 8]);
    }
    __syncthreads();
#pragma unroll
    for (int kk = 0; kk < BK; kk += 32) {
      bf16x8 af[MF], bfr[NF];
#pragma unroll
      for (int mf = 0; mf < MF; ++mf) {
        int r = wm * (BM >> 1) + mf * 16 + ln;
        af[mf] = *(const bf16x8*)&As[r * BK + ((((kk >> 3) + lg) ^ (r & CMASK)) << 3)];
      }
#pragma unroll
      for (int nf = 0; nf < NF; ++nf) {
        int r = wn * (BN >> 1) + nf * 16 + ln;
        bfr[nf] = *(const bf16x8*)&Bs[r * BK + ((((kk >> 3) + lg) ^ (r & CMASK)) << 3)];
      }
#pragma unroll
      for (int mf = 0; mf < MF; ++mf)
#pragma unroll
        for (int nf = 0; nf < NF; ++nf)
          acc[mf][nf] = __builtin_amdgcn_mfma_f32_16x16x32_bf16(af[mf], bfr[nf], acc[mf][nf], 0, 0, 0);
    }
    __syncthreads();
  }
#pragma unroll
  for (int mf = 0; mf < MF; ++mf)
#pragma unroll
    for (int nf = 0; nf < NF; ++nf) {
      int col = n0 + wn * (BN >> 1) + nf * 16 + ln;
      float bv = bias[col];
#pragma unroll
      for (int r = 0; r < 4; ++r) {
        int row = m0 + wm * (BM >> 1) + mf * 16 + lg * 4 + r;
        float val = acc[mf][nf][r] + bv;
        if (EPI == 0) {
          int which = col >> 8, head = (col >> 5) & 7, dd = col & 31;
          int b = row / NT, n = row - b * NT;
          if (which == 2) {
            ((short*)o2)[((size_t)((b * HD + head) * DH + dd)) * NT + n] = f2bf(val);
          } else {
            short* dst = (which == 0) ? (short*)out0 : (short*)o1;
            dst[((size_t)((b * HD + head) * NT + n)) * DH + dd] = f2bf(val);
          }
        } else if (EPI == 1) {
          ((float*)out0)[(size_t)row * Nld + col] = val + res[(size_t)row * Nld + col];
        } else if (EPI == 2) {
          float v2 = val * val;
          float y = val * fmaf(0.102944458f, v2, 2.30225813f);
          y = fminf(y, 80.f);
          float e = __builtin_amdgcn_exp2f(y);
          float gl = val * e * __builtin_amdgcn_rcpf(e + 1.0f);
          ((short*)out0)[(size_t)row * Nld + col] = f2bf(gl);
        } else {
          int b = row / NT, n = row - b * NT;
          ((float*)out0)[((size_t)(b * CC + col)) * NT + n] =
              val + res[(size_t)row * Nld + col];
        }
      }
    }
}

// ---------------- attention: fixed-max flash, QBLK=64, swapped-QK ----------
// + cross-tile bias prefetch (bcur/bnext) and T5 setprio around PV cluster.
__global__ __launch_bounds__(256, 3) void attn_kernel(
    const short* __restrict__ qb, const short* __restrict__ kb,
    const short* __restrict__ vtg, const short* __restrict__ bt,
    short* __restrict__ ob) {
  const int qc = blockIdx.x;  // 0..12
  const int bh = blockIdx.y;  // 0..127
  const int b = bh >> 3, h = bh & 7;
  const int tid = threadIdx.x, lane = tid & 63, wid = tid >> 6;
  const int lg = lane >> 4, ln = lane & 15;
  const int rb = qc * 64 + wid * 16;  // wave's q-row base
  const float SC2 = 0.17677669529663687f * 1.4426950408889634f;  // scale*log2e

  __shared__ short Pl[4][16 * 136];  // per-wave P tile (16 q-rows)
  short* pw = Pl[wid];

  const short* qrow = qb + (size_t)bh * NT * DH;
  bf16x8 aq;
  {
    int r = rb + ln;
    if (r > 783) r = 783;
    aq = *(const bf16x8*)(qrow + (size_t)r * DH + lg * 8);
  }
  float l_acc = 0.f;
  f32x4 o_acc[2] = {};
  const short* kbase = kb + (size_t)bh * NT * DH;
  const short* vbase = vtg + (size_t)bh * DH * NT;
  const short* btw = bt + ((size_t)(h * 13 + qc) * 49) * 1024 + wid * 256 + lane * 4;

  bf16x8 kcur[8];
  u32x2 bcur[8];
#pragma unroll
  for (int nf = 0; nf < 8; ++nf) {
    kcur[nf] = *(const bf16x8*)(kbase + (size_t)(nf * 16 + ln) * DH + lg * 8);
    bcur[nf] = *(const u32x2*)(btw + (size_t)nf * 1024);
  }

  for (int jt = 0; jt < 768; jt += 128) {
    const int jt0 = jt >> 4;
    bf16x8 knext[8];
    u32x2 bnext[8];
#pragma unroll
    for (int nf = 0; nf < 8; ++nf) {
      int j = jt + 128 + nf * 16 + ln;
      if (j > 783) j = 783;
      knext[nf] = *(const bf16x8*)(kbase + (size_t)j * DH + lg * 8);
      // bias for next tile; final iteration over-reads stay inside ws, unused
      bnext[nf] = *(const u32x2*)(btw + (size_t)(jt0 + 8 + nf) * 1024);
    }
    bf16x8 vreg[4][2];
#pragma unroll
    for (int kk = 0; kk < 4; ++kk)
#pragma unroll
      for (int dr = 0; dr < 2; ++dr)
        vreg[kk][dr] = *(const bf16x8*)(vbase + (size_t)(dr * 16 + ln) * NT + jt + kk * 32 + lg * 8);

#pragma unroll
    for (int nf = 0; nf < 8; ++nf) {
      const u32x2 bq = bcur[nf];
      f32x4 zr = {0.f, 0.f, 0.f, 0.f};
      f32x4 s = __builtin_amdgcn_mfma_f32_16x16x32_bf16(kcur[nf], aq, zr, 0, 0, 0);
      unsigned w0 = bq.x, w1 = bq.y;
      float p0 = __builtin_amdgcn_exp2f(fmaf(s[0], SC2, __builtin_bit_cast(float, w0 << 16)));
      float p1 = __builtin_amdgcn_exp2f(fmaf(s[1], SC2, __builtin_bit_cast(float, w0 & 0xffff0000u)));
      float p2 = __builtin_amdgcn_exp2f(fmaf(s[2], SC2, __builtin_bit_cast(float, w1 << 16)));
      float p3 = __builtin_amdgcn_exp2f(fmaf(s[3], SC2, __builtin_bit_cast(float, w1 & 0xffff0000u)));
      l_acc += (p0 + p1) + (p2 + p3);
      u32x2 pk = {pack2bf(p0, p1), pack2bf(p2, p3)};
      *(u32x2*)&pw[ln * 136 + nf * 16 + (lg << 2)] = pk;
    }
    __builtin_amdgcn_s_setprio(1);
#pragma unroll
    for (int kk = 0; kk < 4; ++kk) {
      bf16x8 ap = *(const bf16x8*)&pw[ln * 136 + kk * 32 + lg * 8];
#pragma unroll
      for (int dr = 0; dr < 2; ++dr)
        o_acc[dr] = __builtin_amdgcn_mfma_f32_16x16x32_bf16(ap, vreg[kk][dr], o_acc[dr], 0, 0, 0);
    }
    __builtin_amdgcn_s_setprio(0);
#pragma unroll
    for (int nf = 0; nf < 8; ++nf) {
      kcur[nf] = knext[nf];
      bcur[nf] = bnext[nf];
    }
  }

  // ---- tail tile jt=768 (16 valid columns; kcur[0]/bcur[0] exact) ----
  {
    {
      u32x2 zz = {0u, 0u};
      *(u32x2*)&pw[ln * 136 + 16 + (lg << 2)] = zz;  // zero cols 16..31
    }
    const u32x2 bq = bcur[0];
    f32x4 zr = {0.f, 0.f, 0.f, 0.f};
    f32x4 s = __builtin_amdgcn_mfma_f32_16x16x32_bf16(kcur[0], aq, zr, 0, 0, 0);
    unsigned w0 = bq.x, w1 = bq.y;
    float p0 = __builtin_amdgcn_exp2f(fmaf(s[0], SC2, __builtin_bit_cast(float, w0 << 16)));
    float p1 = __builtin_amdgcn_exp2f(fmaf(s[1], SC2, __builtin_bit_cast(float, w0 & 0xffff0000u)));
    float p2 = __builtin_amdgcn_exp2f(fmaf(s[2], SC2, __builtin_bit_cast(float, w1 << 16)));
    float p3 = __builtin_amdgcn_exp2f(fmaf(s[3], SC2, __builtin_bit_cast(float, w1 & 0xffff0000u)));
    l_acc += (p0 + p1) + (p2 + p3);
    u32x2 pk = {pack2bf(p0, p1), pack2bf(p2, p3)};
    *(u32x2*)&pw[ln * 136 + (lg << 2)] = pk;
    {
      bf16x8 ap = *(const bf16x8*)&pw[ln * 136 + lg * 8];
      bf16x8 bv[2];
#pragma unroll
      for (int dr = 0; dr < 2; ++dr) {
        int col = 768 + lg * 8;
        if (col < NT)
          bv[dr] = *(const bf16x8*)(vbase + (size_t)(dr * 16 + ln) * NT + col);
        else {
          bf16x8 zz = {};
          bv[dr] = zz;
        }
      }
      __builtin_amdgcn_s_setprio(1);
#pragma unroll
      for (int dr = 0; dr < 2; ++dr)
        o_acc[dr] = __builtin_amdgcn_mfma_f32_16x16x32_bf16(ap, bv[dr], o_acc[dr], 0, 0, 0);
      __builtin_amdgcn_s_setprio(0);
    }
  }

  // ---- l reduce: sum over lg (lanes sharing ln), then gather per output row
  l_acc += __shfl_xor(l_acc, 16);
  l_acc += __shfl_xor(l_acc, 32);

  float rinv[4];
#pragma unroll
  for (int r = 0; r < 4; ++r) rinv[r] = 1.0f / __shfl(l_acc, lg * 4 + r);
#pragma unroll
  for (int dr = 0; dr < 2; ++dr)
#pragma unroll
    for (int r = 0; r < 4; ++r) {
      int row = rb + lg * 4 + r;
      if (row < 784) {
        float val = o_acc[dr][r] * rinv[r];
        ob[((size_t)(b * NT + row)) * INNER + h * DH + dr * 16 + ln] = f2bf(val);
      }
    }
}

// ---------------------------------------------------------------------------
extern "C" void kernel_launch(void* const* d_in, const int* in_sizes, int n_in,
                              void* d_out, int out_size, void* d_ws, size_t ws_size,
                              hipStream_t stream) {
  const float* x = (const float*)d_in[0];
  const float* ln1_g = (const float*)d_in[1];
  const float* ln1_b = (const float*)d_in[2];
  const float* qkv_w = (const float*)d_in[3];
  const float* qkv_b = (const float*)d_in[4];
  const float* out_w = (const float*)d_in[5];
  const float* out_b = (const float*)d_in[6];
  const float* rel_table = (const float*)d_in[7];
  const float* ln2_g = (const float*)d_in[8];
  const float* ln2_b = (const float*)d_in[9];
  const float* ff_w1 = (const float*)d_in[10];
  const float* ff_b1 = (const float*)d_in[11];
  const float* ff_w2 = (const float*)d_in[12];
  const float* ff_b2 = (const float*)d_in[13];
  float* out = (float*)d_out;
  char* ws = (char*)d_ws;

  constexpr size_t OFF_XS = 0;          // f32 [12544][512]
  constexpr size_t OFF_H = 25690112;    // bf16 [12544][512]
  constexpr size_t OFF_WQKV = 38535168; // bf16 [768][512]
  constexpr size_t OFF_WOUT = 39321600; // bf16 [512][256]
  constexpr size_t OFF_WF1 = 39583744;  // bf16 [2048][512]
  constexpr size_t OFF_WF2 = 41680896;  // bf16 [512][2048]
  constexpr size_t OFF_Q = 43778048;    // bf16 [128][784][32]
  constexpr size_t OFF_K = 50200576;
  constexpr size_t OFF_VT = 63045632;   // bf16 [128][32][784]
  constexpr size_t OFF_O = 69468160;    // bf16 [12544][256]
  constexpr size_t OFF_XS2 = 75890688;  // f32 [12544][512]; bias table lives here pre-attn
  constexpr size_t OFF_G = 101580800;   // bf16 [12544][2048]

  float* xs = (float*)(ws + OFF_XS);
  short* h = (short*)(ws + OFF_H);
  short* wqkvT = (short*)(ws + OFF_WQKV);
  short* woutT = (short*)(ws + OFF_WOUT);
  short* wf1T = (short*)(ws + OFF_WF1);
  short* wf2T = (short*)(ws + OFF_WF2);
  short* qb = (short*)(ws + OFF_Q);
  short* kb = (short*)(ws + OFF_K);
  short* vt = (short*)(ws + OFF_VT);
  short* ob = (short*)(ws + OFF_O);
  short* bt = (short*)(ws + OFF_XS2);   // bf16 QBLK=64 table, 10.4 MB (dead after attn)
  float* xs2 = (float*)(ws + OFF_XS2);
  short* g = (short*)(ws + OFF_G);

  // mega-prep: weight transposes + fused xtrans+LN1 + bias table
  prep_kernel<<<23728, 256, 0, stream>>>(qkv_w, wqkvT, out_w, woutT,
                                         ff_w1, wf1T, ff_w2, wf2T,
                                         x, xs, ln1_g, ln1_b, h, rel_table, bt);

  // QKV (V written directly transposed; BN=64 -> grid 1176)
  gemm_bt<0, 128, 64, 64, 3><<<1176, 256, 0, stream>>>(h, wqkvT, qkv_b, 512, qb, kb, vt, nullptr, 0, 12);

  // attention (QBLK=64, swapped-QK, bias prefetch + setprio; grid 13x128)
  attn_kernel<<<dim3(13, 128), 256, 0, stream>>>(qb, kb, vt, bt, ob);

  // out-proj + residual -> xs2   (N=512, BN=64 -> grid 784)
  gemm_bt<1, 128, 64, 64, 3><<<784, 256, 0, stream>>>(ob, woutT, out_b, 256, xs2, nullptr, nullptr, xs, 512, 8);

  // LN2 -> h2
  ln_kernel<<<MTOT, 256, 0, stream>>>(xs2, ln2_g, ln2_b, h);

  // FFN1 + fast GELU -> g
  gemm_bt<2, 128, 128, 64, 3><<<1568, 256, 0, stream>>>(h, wf1T, ff_b1, 512, g, nullptr, nullptr, nullptr, 2048, 16);

  // FFN2 + residual -> out (transposed write)
  gemm_bt<3, 128, 64, 64, 3><<<784, 256, 0, stream>>>(g, wf2T, ff_b2, 2048, out, nullptr, nullptr, xs2, 512, 8);
}

// Round 21
// 219.335 us; speedup vs baseline: 1.0544x; 1.0025x over previous
//
#include <hip/hip_runtime.h>
#include <hip/hip_bf16.h>

#define DEVI __device__ __forceinline__

typedef __attribute__((ext_vector_type(8))) short bf16x8;
typedef __attribute__((ext_vector_type(4))) float f32x4;
typedef __attribute__((ext_vector_type(2))) unsigned u32x2;

static constexpr int BB = 16, CC = 512, NT = 784, HD = 8, DH = 32;
static constexpr int INNER = 256, HID = 2048, MTOT = BB * NT; // 12544

DEVI short f2bf(float x) {
  unsigned u = __builtin_bit_cast(unsigned, x);
  u += 0x7fffu + ((u >> 16) & 1u);
  return (short)(u >> 16);
}

DEVI unsigned pack2bf(float lo, float hi) {
  return ((unsigned)(unsigned short)f2bf(lo)) | ((unsigned)(unsigned short)f2bf(hi) << 16);
}

DEVI void gll16(const void* g, void* l) {
  __builtin_amdgcn_global_load_lds(
      (const __attribute__((address_space(1))) unsigned int*)g,
      (__attribute__((address_space(3))) unsigned int*)l, 16, 0, 0);
}

// ---------------- mega-prep: weight transposes + fused xtrans+LN1 + biastab -
__device__ void wprep_body(const float* __restrict__ W, short* __restrict__ WT,
                           int K0, int N0, int bx, int by, float* smem) {
  float (*tile)[33] = (float(*)[33])smem;
  const int tk0 = bx * 32, tn0 = by * 32;
  const int tx = threadIdx.x & 31, ty = threadIdx.x >> 5;  // 32 x 8
#pragma unroll
  for (int i = 0; i < 4; ++i)
    tile[ty + i * 8][tx] = W[(size_t)(tk0 + ty + i * 8) * N0 + tn0 + tx];
  __syncthreads();
#pragma unroll
  for (int i = 0; i < 4; ++i)
    WT[(size_t)(tn0 + ty + i * 8) * K0 + tk0 + tx] = f2bf(tile[tx][ty + i * 8]);
}

__global__ void prep_kernel(const float* __restrict__ qkv_w, short* __restrict__ wqkvT,
                            const float* __restrict__ out_w, short* __restrict__ woutT,
                            const float* __restrict__ ff_w1, short* __restrict__ wf1T,
                            const float* __restrict__ ff_w2, short* __restrict__ wf2T,
                            const float* __restrict__ x, float* __restrict__ xs,
                            const float* __restrict__ gw, const float* __restrict__ bw,
                            short* __restrict__ h1,
                            const float* __restrict__ rel, short* __restrict__ bt) {
  __shared__ float smem[512 * 17];
  __shared__ float stats[32];
  const int bid = blockIdx.x;
  if (bid < 384) {
    wprep_body(qkv_w, wqkvT, 512, 768, bid & 15, bid >> 4, smem);
  } else if (bid < 512) {
    int l = bid - 384;
    wprep_body(out_w, woutT, 256, 512, l & 7, l >> 3, smem);
  } else if (bid < 1536) {
    int l = bid - 512;
    wprep_body(ff_w1, wf1T, 512, 2048, l & 15, l >> 4, smem);
  } else if (bid < 2560) {
    int l = bid - 1536;
    wprep_body(ff_w2, wf2T, 2048, 512, l & 63, l >> 6, smem);
  } else if (bid < 3344) {
    // fused x-transpose + LN1: 16 tokens per block
    int l = bid - 2560;            // 0..783
    int b = l / 49, n0 = (l % 49) * 16;
    float (*tile)[17] = (float(*)[17])smem;  // [512 c][16 n, pad 17]
    const int tx = threadIdx.x & 15, ty = threadIdx.x >> 4;  // n, c-in-16
    const float* px = x + (size_t)b * CC * NT + n0;
#pragma unroll
    for (int c0 = 0; c0 < 512; c0 += 16)
      tile[c0 + ty][tx] = px[(size_t)(c0 + ty) * NT + tx];
    __syncthreads();
    // write xs (coalesced: lanes over c)
    float* qd = xs + ((size_t)b * NT + n0) * CC;
    const int c1 = threadIdx.x, c2 = threadIdx.x + 256;
#pragma unroll
    for (int nn = 0; nn < 16; ++nn) {
      qd[(size_t)nn * CC + c1] = tile[c1][nn];
      qd[(size_t)nn * CC + c2] = tile[c2][nn];
    }
    // LN stats: 16 threads per token (cl = c-lane, t = token)
    const int cl = threadIdx.x & 15, t = threadIdx.x >> 4;
    float s = 0.f, s2 = 0.f;
#pragma unroll
    for (int i = 0; i < 32; ++i) {
      float v = tile[cl + 16 * i][t];
      s += v;
      s2 += v * v;
    }
#pragma unroll
    for (int m = 1; m < 16; m <<= 1) {
      s += __shfl_xor(s, m);
      s2 += __shfl_xor(s2, m);
    }
    float mu = s * (1.f / 512.f);
    float var = s2 * (1.f / 512.f) - mu * mu;
    float rs = rsqrtf(var + 1e-5f);
    if (cl == 0) { stats[t] = mu; stats[16 + t] = rs; }
    __syncthreads();
    short* hd = h1 + ((size_t)b * NT + n0) * CC;
    const float g1 = gw[c1], b1 = bw[c1], g2 = gw[c2], b2 = bw[c2];
#pragma unroll
    for (int nn = 0; nn < 16; ++nn) {
      float m_ = stats[nn], r_ = stats[16 + nn];
      hd[(size_t)nn * CC + c1] = f2bf((tile[c1][nn] - m_) * r_ * g1 + b1);
      hd[(size_t)nn * CC + c2] = f2bf((tile[c2][nn] - m_) * r_ * g2 + b2);
    }
  } else {
    // biastab (swapped-QK layout): bt[h][qc13][jblk49][wid][lane][r]
    //   i = qc*64 + wid*16 + (lane&15)            (clamped to 783)
    //   j = jblk*16 + (lane>>4)*4 + r
    int id = (bid - 3344) * 256 + threadIdx.x;  // 8*13*49*4*64*4 = 5218304
    int r = id & 3;
    int lane = (id >> 2) & 63;
    int wid = (id >> 8) & 3;
    int t = id >> 10;          // jblk + 49*(qc + 13*h)
    int jblk = t % 49;
    int t2 = t / 49;
    int qc = t2 % 13;
    int h = t2 / 13;
    int i = qc * 64 + wid * 16 + (lane & 15);
    if (i > 783) i = 783;
    int j = jblk * 16 + ((lane >> 4) << 2) + r;
    int hi_ = i / 28, wi_ = i - hi_ * 28;
    int hj = j / 28, wj = j - hj * 28;
    int ridx = (hi_ - hj + 27) * 55 + (wi_ - wj + 27);
    bt[id] = f2bf(rel[ridx * 8 + h] * 1.4426950408889634f);
  }
}

// ---------------- LayerNorm (block = 1 token, 256 thr, C=512, coalesced) ----
__global__ void ln_kernel(const float* __restrict__ in, const float* __restrict__ gw,
                          const float* __restrict__ bw, short* __restrict__ h_out) {
  int t = blockIdx.x;
  int tid = threadIdx.x;
  const float* p = in + (size_t)t * CC;
  float v0 = p[tid], v1 = p[tid + 256];
  float s = v0 + v1, s2 = v0 * v0 + v1 * v1;
#pragma unroll
  for (int m = 1; m < 64; m <<= 1) {
    s += __shfl_xor(s, m);
    s2 += __shfl_xor(s2, m);
  }
  __shared__ float red[8];
  int wid = tid >> 6;
  if ((tid & 63) == 0) { red[wid] = s; red[4 + wid] = s2; }
  __syncthreads();
  s = red[0] + red[1] + red[2] + red[3];
  s2 = red[4] + red[5] + red[6] + red[7];
  float mu = s * (1.f / 512.f);
  float var = s2 * (1.f / 512.f) - mu * mu;
  float rs = rsqrtf(var + 1e-5f);
  h_out[(size_t)t * CC + tid] = f2bf((v0 - mu) * rs * gw[tid] + bw[tid]);
  h_out[(size_t)t * CC + tid + 256] = f2bf((v1 - mu) * rs * gw[tid + 256] + bw[tid + 256]);
}

// ---------------- GEMM: C[m][n] = sum_k A[m][k] * BT[n][k] ------------------
// Single-buffer, T2 XOR-swizzled LDS (CHUNKS=BK/8 chunk bits),
// bijective XCD-chunk swizzle (n-fastest). BK=64.
template <int EPI, int BM, int BN, int BK, int MINW>
__global__ __launch_bounds__(256, MINW) void gemm_bt(
    const short* __restrict__ A, const short* __restrict__ BT,
    const float* __restrict__ bias, int K, void* __restrict__ out0,
    void* __restrict__ o1, void* __restrict__ o2, const float* __restrict__ res,
    int Nld, int nn) {
  __shared__ short As[BM * BK];
  __shared__ short Bs[BN * BK];
  const int tid = threadIdx.x;
  const int lane = tid & 63, wid = tid >> 6;
  const int nwg = gridDim.x, orig = blockIdx.x;
  const int q = nwg >> 3, rm = nwg & 7;
  const int xcd = orig & 7, idx = orig >> 3;
  const int wg = (xcd < rm) ? (xcd * (q + 1) + idx)
                            : (rm * (q + 1) + (xcd - rm) * q + idx);
  const int mt = wg / nn, nt = wg - mt * nn;
  const int m0 = mt * BM, n0 = nt * BN;
  const int wm = wid >> 1, wn = wid & 1;
  constexpr int MF = BM >> 5;
  constexpr int NF = BN >> 5;
  constexpr int CHUNKS = BK / 8;                 // 16B chunks per row
  constexpr int CMASK = CHUNKS - 1;
  constexpr int ACALLS = (BM * CHUNKS) / 256;
  constexpr int BCALLS = (BN * CHUNKS) / 256;
  const int lg = lane >> 4, ln = lane & 15;

  f32x4 acc[MF][NF] = {};
  for (int kt = 0; kt < K; kt += BK) {
#pragma unroll
    for (int call = 0; call < ACALLS; ++call) {
      int cb = call * 256 + (wid << 6);
      int c = cb + lane;
      int row = c / CHUNKS, j8 = c & CMASK;
      gll16(A + (size_t)(m0 + row) * K + kt + (j8 ^ (row & CMASK)) * 8, &As[cb * 8]);
    }
#pragma unroll
    for (int call = 0; call < BCALLS; ++call) {
      int cb = call * 256 + (wid << 6);
      int c = cb + lane;
      int row = c / CHUNKS, j8 = c & CMASK;
      gll16(BT + (size_t)(n0 + row) * K + kt + (j8 ^ (row & CMASK)) * 8, &Bs[cb * 8]);
    }
    __syncthreads();
#pragma unroll
    for (int kk = 0; kk < BK; kk += 32) {
      bf16x8 af[MF], bfr[NF];
#pragma unroll
      for (int mf = 0; mf < MF; ++mf) {
        int r = wm * (BM >> 1) + mf * 16 + ln;
        af[mf] = *(const bf16x8*)&As[r * BK + ((((kk >> 3) + lg) ^ (r & CMASK)) << 3)];
      }
#pragma unroll
      for (int nf = 0; nf < NF; ++nf) {
        int r = wn * (BN >> 1) + nf * 16 + ln;
        bfr[nf] = *(const bf16x8*)&Bs[r * BK + ((((kk >> 3) + lg) ^ (r & CMASK)) << 3)];
      }
#pragma unroll
      for (int mf = 0; mf < MF; ++mf)
#pragma unroll
        for (int nf = 0; nf < NF; ++nf)
          acc[mf][nf] = __builtin_amdgcn_mfma_f32_16x16x32_bf16(af[mf], bfr[nf], acc[mf][nf], 0, 0, 0);
    }
    __syncthreads();
  }
#pragma unroll
  for (int mf = 0; mf < MF; ++mf)
#pragma unroll
    for (int nf = 0; nf < NF; ++nf) {
      int col = n0 + wn * (BN >> 1) + nf * 16 + ln;
      float bv = bias[col];
#pragma unroll
      for (int r = 0; r < 4; ++r) {
        int row = m0 + wm * (BM >> 1) + mf * 16 + lg * 4 + r;
        float val = acc[mf][nf][r] + bv;
        if (EPI == 0) {
          int which = col >> 8, head = (col >> 5) & 7, dd = col & 31;
          int b = row / NT, n = row - b * NT;
          if (which == 2) {
            ((short*)o2)[((size_t)((b * HD + head) * DH + dd)) * NT + n] = f2bf(val);
          } else {
            short* dst = (which == 0) ? (short*)out0 : (short*)o1;
            dst[((size_t)((b * HD + head) * NT + n)) * DH + dd] = f2bf(val);
          }
        } else if (EPI == 1) {
          ((float*)out0)[(size_t)row * Nld + col] = val + res[(size_t)row * Nld + col];
        } else if (EPI == 2) {
          float v2 = val * val;
          float y = val * fmaf(0.102944458f, v2, 2.30225813f);
          y = fminf(y, 80.f);
          float e = __builtin_amdgcn_exp2f(y);
          float gl = val * e * __builtin_amdgcn_rcpf(e + 1.0f);
          ((short*)out0)[(size_t)row * Nld + col] = f2bf(gl);
        } else {
          int b = row / NT, n = row - b * NT;
          ((float*)out0)[((size_t)(b * CC + col)) * NT + n] =
              val + res[(size_t)row * Nld + col];
        }
      }
    }
}

// ---------------- attention: fixed-max flash, QBLK=64, swapped-QK ----------
// (r19 version: no bias prefetch, no setprio — 60 VGPR / 33% occupancy config)
__global__ __launch_bounds__(256, 3) void attn_kernel(
    const short* __restrict__ qb, const short* __restrict__ kb,
    const short* __restrict__ vtg, const short* __restrict__ bt,
    short* __restrict__ ob) {
  const int qc = blockIdx.x;  // 0..12
  const int bh = blockIdx.y;  // 0..127
  const int b = bh >> 3, h = bh & 7;
  const int tid = threadIdx.x, lane = tid & 63, wid = tid >> 6;
  const int lg = lane >> 4, ln = lane & 15;
  const int rb = qc * 64 + wid * 16;  // wave's q-row base
  const float SC2 = 0.17677669529663687f * 1.4426950408889634f;  // scale*log2e

  __shared__ short Pl[4][16 * 136];  // per-wave P tile (16 q-rows)
  short* pw = Pl[wid];

  const short* qrow = qb + (size_t)bh * NT * DH;
  bf16x8 aq;
  {
    int r = rb + ln;
    if (r > 783) r = 783;
    aq = *(const bf16x8*)(qrow + (size_t)r * DH + lg * 8);
  }
  float l_acc = 0.f;
  f32x4 o_acc[2] = {};
  const short* kbase = kb + (size_t)bh * NT * DH;
  const short* vbase = vtg + (size_t)bh * DH * NT;
  const short* btw = bt + ((size_t)(h * 13 + qc) * 49) * 1024 + wid * 256 + lane * 4;

  bf16x8 kcur[8];
#pragma unroll
  for (int nf = 0; nf < 8; ++nf)
    kcur[nf] = *(const bf16x8*)(kbase + (size_t)(nf * 16 + ln) * DH + lg * 8);

  for (int jt = 0; jt < 768; jt += 128) {
    const int jt0 = jt >> 4;
    bf16x8 knext[8];
#pragma unroll
    for (int nf = 0; nf < 8; ++nf) {
      int j = jt + 128 + nf * 16 + ln;
      if (j > 783) j = 783;
      knext[nf] = *(const bf16x8*)(kbase + (size_t)j * DH + lg * 8);
    }
    bf16x8 vreg[4][2];
#pragma unroll
    for (int kk = 0; kk < 4; ++kk)
#pragma unroll
      for (int dr = 0; dr < 2; ++dr)
        vreg[kk][dr] = *(const bf16x8*)(vbase + (size_t)(dr * 16 + ln) * NT + jt + kk * 32 + lg * 8);

#pragma unroll
    for (int nf = 0; nf < 8; ++nf) {
      const u32x2 bq = *(const u32x2*)(btw + (size_t)(jt0 + nf) * 1024);
      f32x4 zr = {0.f, 0.f, 0.f, 0.f};
      f32x4 s = __builtin_amdgcn_mfma_f32_16x16x32_bf16(kcur[nf], aq, zr, 0, 0, 0);
      unsigned w0 = bq.x, w1 = bq.y;
      float p0 = __builtin_amdgcn_exp2f(fmaf(s[0], SC2, __builtin_bit_cast(float, w0 << 16)));
      float p1 = __builtin_amdgcn_exp2f(fmaf(s[1], SC2, __builtin_bit_cast(float, w0 & 0xffff0000u)));
      float p2 = __builtin_amdgcn_exp2f(fmaf(s[2], SC2, __builtin_bit_cast(float, w1 << 16)));
      float p3 = __builtin_amdgcn_exp2f(fmaf(s[3], SC2, __builtin_bit_cast(float, w1 & 0xffff0000u)));
      l_acc += (p0 + p1) + (p2 + p3);
      u32x2 pk = {pack2bf(p0, p1), pack2bf(p2, p3)};
      *(u32x2*)&pw[ln * 136 + nf * 16 + (lg << 2)] = pk;
    }
#pragma unroll
    for (int kk = 0; kk < 4; ++kk) {
      bf16x8 ap = *(const bf16x8*)&pw[ln * 136 + kk * 32 + lg * 8];
#pragma unroll
      for (int dr = 0; dr < 2; ++dr)
        o_acc[dr] = __builtin_amdgcn_mfma_f32_16x16x32_bf16(ap, vreg[kk][dr], o_acc[dr], 0, 0, 0);
    }
#pragma unroll
    for (int nf = 0; nf < 8; ++nf) kcur[nf] = knext[nf];
  }

  // ---- tail tile jt=768 (16 valid columns; kcur[0] holds exact rows 768..783)
  {
    {
      u32x2 zz = {0u, 0u};
      *(u32x2*)&pw[ln * 136 + 16 + (lg << 2)] = zz;  // zero cols 16..31
    }
    const u32x2 bq = *(const u32x2*)(btw + (size_t)48 * 1024);
    f32x4 zr = {0.f, 0.f, 0.f, 0.f};
    f32x4 s = __builtin_amdgcn_mfma_f32_16x16x32_bf16(kcur[0], aq, zr, 0, 0, 0);
    unsigned w0 = bq.x, w1 = bq.y;
    float p0 = __builtin_amdgcn_exp2f(fmaf(s[0], SC2, __builtin_bit_cast(float, w0 << 16)));
    float p1 = __builtin_amdgcn_exp2f(fmaf(s[1], SC2, __builtin_bit_cast(float, w0 & 0xffff0000u)));
    float p2 = __builtin_amdgcn_exp2f(fmaf(s[2], SC2, __builtin_bit_cast(float, w1 << 16)));
    float p3 = __builtin_amdgcn_exp2f(fmaf(s[3], SC2, __builtin_bit_cast(float, w1 & 0xffff0000u)));
    l_acc += (p0 + p1) + (p2 + p3);
    u32x2 pk = {pack2bf(p0, p1), pack2bf(p2, p3)};
    *(u32x2*)&pw[ln * 136 + (lg << 2)] = pk;
    {
      bf16x8 ap = *(const bf16x8*)&pw[ln * 136 + lg * 8];
      bf16x8 bv[2];
#pragma unroll
      for (int dr = 0; dr < 2; ++dr) {
        int col = 768 + lg * 8;
        if (col < NT)
          bv[dr] = *(const bf16x8*)(vbase + (size_t)(dr * 16 + ln) * NT + col);
        else {
          bf16x8 zz = {};
          bv[dr] = zz;
        }
      }
#pragma unroll
      for (int dr = 0; dr < 2; ++dr)
        o_acc[dr] = __builtin_amdgcn_mfma_f32_16x16x32_bf16(ap, bv[dr], o_acc[dr], 0, 0, 0);
    }
  }

  // ---- l reduce: sum over lg (lanes sharing ln), then gather per output row
  l_acc += __shfl_xor(l_acc, 16);
  l_acc += __shfl_xor(l_acc, 32);

  float rinv[4];
#pragma unroll
  for (int r = 0; r < 4; ++r) rinv[r] = 1.0f / __shfl(l_acc, lg * 4 + r);
#pragma unroll
  for (int dr = 0; dr < 2; ++dr)
#pragma unroll
    for (int r = 0; r < 4; ++r) {
      int row = rb + lg * 4 + r;
      if (row < 784) {
        float val = o_acc[dr][r] * rinv[r];
        ob[((size_t)(b * NT + row)) * INNER + h * DH + dr * 16 + ln] = f2bf(val);
      }
    }
}

// ---------------------------------------------------------------------------
extern "C" void kernel_launch(void* const* d_in, const int* in_sizes, int n_in,
                              void* d_out, int out_size, void* d_ws, size_t ws_size,
                              hipStream_t stream) {
  const float* x = (const float*)d_in[0];
  const float* ln1_g = (const float*)d_in[1];
  const float* ln1_b = (const float*)d_in[2];
  const float* qkv_w = (const float*)d_in[3];
  const float* qkv_b = (const float*)d_in[4];
  const float* out_w = (const float*)d_in[5];
  const float* out_b = (const float*)d_in[6];
  const float* rel_table = (const float*)d_in[7];
  const float* ln2_g = (const float*)d_in[8];
  const float* ln2_b = (const float*)d_in[9];
  const float* ff_w1 = (const float*)d_in[10];
  const float* ff_b1 = (const float*)d_in[11];
  const float* ff_w2 = (const float*)d_in[12];
  const float* ff_b2 = (const float*)d_in[13];
  float* out = (float*)d_out;
  char* ws = (char*)d_ws;

  constexpr size_t OFF_XS = 0;          // f32 [12544][512]
  constexpr size_t OFF_H = 25690112;    // bf16 [12544][512]
  constexpr size_t OFF_WQKV = 38535168; // bf16 [768][512]
  constexpr size_t OFF_WOUT = 39321600; // bf16 [512][256]
  constexpr size_t OFF_WF1 = 39583744;  // bf16 [2048][512]
  constexpr size_t OFF_WF2 = 41680896;  // bf16 [512][2048]
  constexpr size_t OFF_Q = 43778048;    // bf16 [128][784][32]
  constexpr size_t OFF_K = 50200576;
  constexpr size_t OFF_VT = 63045632;   // bf16 [128][32][784]
  constexpr size_t OFF_O = 69468160;    // bf16 [12544][256]
  constexpr size_t OFF_XS2 = 75890688;  // f32 [12544][512]; bias table lives here pre-attn
  constexpr size_t OFF_G = 101580800;   // bf16 [12544][2048]

  float* xs = (float*)(ws + OFF_XS);
  short* h = (short*)(ws + OFF_H);
  short* wqkvT = (short*)(ws + OFF_WQKV);
  short* woutT = (short*)(ws + OFF_WOUT);
  short* wf1T = (short*)(ws + OFF_WF1);
  short* wf2T = (short*)(ws + OFF_WF2);
  short* qb = (short*)(ws + OFF_Q);
  short* kb = (short*)(ws + OFF_K);
  short* vt = (short*)(ws + OFF_VT);
  short* ob = (short*)(ws + OFF_O);
  short* bt = (short*)(ws + OFF_XS2);   // bf16 QBLK=64 table, 10.4 MB (dead after attn)
  float* xs2 = (float*)(ws + OFF_XS2);
  short* g = (short*)(ws + OFF_G);

  // mega-prep: weight transposes + fused xtrans+LN1 + bias table
  prep_kernel<<<23728, 256, 0, stream>>>(qkv_w, wqkvT, out_w, woutT,
                                         ff_w1, wf1T, ff_w2, wf2T,
                                         x, xs, ln1_g, ln1_b, h, rel_table, bt);

  // QKV (V written directly transposed; BN=64 -> grid 1176)
  gemm_bt<0, 128, 64, 64, 3><<<1176, 256, 0, stream>>>(h, wqkvT, qkv_b, 512, qb, kb, vt, nullptr, 0, 12);

  // attention (QBLK=64, swapped-QK; grid 13x128)
  attn_kernel<<<dim3(13, 128), 256, 0, stream>>>(qb, kb, vt, bt, ob);

  // out-proj + residual -> xs2   (N=512, BN=64 -> grid 784)
  gemm_bt<1, 128, 64, 64, 3><<<784, 256, 0, stream>>>(ob, woutT, out_b, 256, xs2, nullptr, nullptr, xs, 512, 8);

  // LN2 -> h2
  ln_kernel<<<MTOT, 256, 0, stream>>>(xs2, ln2_g, ln2_b, h);

  // FFN1 + fast GELU -> g
  gemm_bt<2, 128, 128, 64, 3><<<1568, 256, 0, stream>>>(h, wf1T, ff_b1, 512, g, nullptr, nullptr, nullptr, 2048, 16);

  // FFN2 + residual -> out (transposed write)
  gemm_bt<3, 128, 64, 64, 3><<<784, 256, 0, stream>>>(g, wf2T, ff_b2, 2048, out, nullptr, nullptr, xs2, 512, 8);
}